// Round 1
// baseline (448.371 us; speedup 1.0000x reference)
//
#include <hip/hip_runtime.h>
#include <stdint.h>

#define HID    1024
#define TYPES  1001
#define MPAD   1024
#define NGATES 5120              // 5 gates * 1024
#define BATCH  32
#define SEQLEN 512
#define TB     (BATCH * SEQLEN)  // 16384
#define TBH    ((size_t)TB * HID)          // 16,777,216 floats per output plane
#define GSTRIDE ((size_t)MPAD * HID)       // 1,048,576 floats per gate plane

typedef __attribute__((ext_vector_type(4))) float  f32x4;
typedef __attribute__((ext_vector_type(8))) __bf16 bf16x8;

// round-to-nearest-even f32 -> bf16 bits
__device__ __forceinline__ uint32_t f2bf(float f) {
    uint32_t u = __float_as_uint(f);
    return (u + 0x7FFFu + ((u >> 16) & 1u)) >> 16;
}

// gate g in {0:gi,1:gz,2:go,3:gib,4:gd} -> source row offset in W_rec / b_rec
// offsets: gi=0, gz=2048, go=3072, gib=4096, gd=6144
__device__ __forceinline__ int gate_off(int g) {
    return (g + (g >= 1) + (g >= 4)) << 10;
}

// async global->LDS, 16B per lane (LDS dest must be uniform-base + lane*16)
#define GLD16(gp, lp) __builtin_amdgcn_global_load_lds(                        \
    (const __attribute__((address_space(1))) void*)(uintptr_t)(gp),            \
    (__attribute__((address_space(3))) void*)(uint32_t)(uintptr_t)(lp),        \
    16, 0, 0)

// ---------------------------------------------------------------------------
// Kernel 1: convert emb (1001x1024) and gathered W rows (5120x1024) to bf16.
// grid = TYPES + NGATES blocks, 256 threads, one row (1024 elems) per block.
// ---------------------------------------------------------------------------
__global__ __launch_bounds__(256) void convert_kernel(
    const float* __restrict__ emb, const float* __restrict__ Wrec,
    uint16_t* __restrict__ Ebf, uint16_t* __restrict__ Wbf)
{
    const int row = blockIdx.x;
    const int tid = threadIdx.x;
    const float* src;
    uint16_t* dst;
    if (row < TYPES) {
        src = emb + (size_t)row * HID;
        dst = Ebf + (size_t)row * HID;
    } else {
        const int n = row - TYPES;           // 0..5119
        const int g = n >> 10;
        const int h = n & 1023;
        src = Wrec + (size_t)(gate_off(g) + h) * (2 * HID);  // W_rec row stride = 2H
        dst = Wbf + (size_t)n * HID;
    }
    float4 v = ((const float4*)src)[tid];
    uint2 p;
    p.x = f2bf(v.x) | (f2bf(v.y) << 16);
    p.y = f2bf(v.z) | (f2bf(v.w) << 16);
    ((uint2*)dst)[tid] = p;
}

// ---------------------------------------------------------------------------
// Kernel 2: bf16 MFMA GEMM  G_raw[m,n] = E[m,:] . W[n,:] + bias(n), then
// per-gate activation, store fp32 table G[g][m][h], g = n>>10, h = n&1023.
// 128x128 tile, BK=32, 256 threads (4 waves, each 64x64 = 4x4 MFMA subtiles).
// grid = (8, 40). Rows 1001..1023 are garbage (never read downstream).
// ---------------------------------------------------------------------------
__global__ __launch_bounds__(256) void gemm_gates(
    const uint16_t* __restrict__ E, const uint16_t* __restrict__ W,
    const float* __restrict__ brec, float* __restrict__ G)
{
    __shared__ uint16_t As[128 * 32];
    __shared__ uint16_t Bs[128 * 32];
    const int tM = blockIdx.x;      // 0..7
    const int tN = blockIdx.y;      // 0..39
    const int t = threadIdx.x;
    const int wave = t >> 6;
    const int lane = t & 63;
    const int lane15 = lane & 15;
    const int quad = lane >> 4;
    const int m0 = (wave >> 1) * 64;
    const int n0 = (wave & 1) * 64;

    f32x4 acc[4][4] = {};

    // staging: thread t loads 16B = 8 bf16: row = t/4 (+64), chunk = (t&3)*8
    const uint16_t* Ag = E + (size_t)(tM * 128 + (t >> 2)) * HID + (t & 3) * 8;
    const uint16_t* Bg = W + (size_t)(tN * 128 + (t >> 2)) * HID + (t & 3) * 8;
    uint16_t* Al = &As[(t >> 2) * 32 + (t & 3) * 8];
    uint16_t* Bl = &Bs[(t >> 2) * 32 + (t & 3) * 8];

    for (int k0 = 0; k0 < HID; k0 += 32) {
        GLD16(Ag + k0, Al);
        GLD16(Ag + k0 + (size_t)64 * HID, Al + 64 * 32);
        GLD16(Bg + k0, Bl);
        GLD16(Bg + k0 + (size_t)64 * HID, Bl + 64 * 32);
        __syncthreads();   // compiler drains vmcnt before s_barrier

        bf16x8 af[4], bfr[4];
        #pragma unroll
        for (int i = 0; i < 4; i++)
            af[i] = *(const bf16x8*)&As[(m0 + i * 16 + lane15) * 32 + quad * 8];
        #pragma unroll
        for (int i = 0; i < 4; i++)
            bfr[i] = *(const bf16x8*)&Bs[(n0 + i * 16 + lane15) * 32 + quad * 8];

        #pragma unroll
        for (int im = 0; im < 4; im++)
            #pragma unroll
            for (int in = 0; in < 4; in++)
                acc[im][in] = __builtin_amdgcn_mfma_f32_16x16x32_bf16(
                    af[im], bfr[in], acc[im][in], 0, 0, 0);
        __syncthreads();
    }

    // epilogue: C/D layout col = lane&15, row = quad*4 + reg  [m89/m91]
    #pragma unroll
    for (int in = 0; in < 4; in++) {
        const int n = tN * 128 + n0 + in * 16 + lane15;
        const int g = n >> 10;          // wave-uniform (16-aligned subtiles)
        const int h = n & 1023;
        const float bias = brec[gate_off(g) + h];
        float* Gg = G + (size_t)g * GSTRIDE + h;
        #pragma unroll
        for (int im = 0; im < 4; im++) {
            const int mb = tM * 128 + m0 + im * 16 + quad * 4;
            #pragma unroll
            for (int r = 0; r < 4; r++) {
                const float v = acc[im][in][r] + bias;
                float o;
                if (g == 1) {                       // gz: tanh
                    float e = __expf(2.f * v);
                    o = 1.f - 2.f / (e + 1.f);
                } else if (g == 4) {                // gd: softplus (stable)
                    o = fmaxf(v, 0.f) + log1pf(__expf(-fabsf(v)));
                } else {                            // gi/go/gib: sigmoid
                    o = 1.f / (1.f + __expf(-v));
                }
                Gg[(size_t)(mb + r) * HID] = o;
            }
        }
    }
}

// ---------------------------------------------------------------------------
// Kernel 3: broadcast/expand. One block per (t,b): gather the 5 table rows for
// type u, compute duration-dependent h_d, write all 5 output planes.
// out[s, t, b, h] ; s in {h_d, c, c_bar, go, gd}
// ---------------------------------------------------------------------------
__global__ __launch_bounds__(256) void expand_kernel(
    const int* __restrict__ ev, const float* __restrict__ dur,
    const float* __restrict__ G, float* __restrict__ out)
{
    const int tb = blockIdx.x;       // = t*32 + b
    const int t = tb >> 5;
    const int b = tb & 31;
    const int src = b * SEQLEN + t;  // inputs are [B, T]
    const int u = ev[src];
    const float d = dur[src];
    const int tid = threadIdx.x;

    const float* Gu = G + (size_t)u * HID;
    f32x4 gi  = *((const f32x4*)(Gu + 0 * GSTRIDE) + tid);
    f32x4 gz  = *((const f32x4*)(Gu + 1 * GSTRIDE) + tid);
    f32x4 go  = *((const f32x4*)(Gu + 2 * GSTRIDE) + tid);
    f32x4 gib = *((const f32x4*)(Gu + 3 * GSTRIDE) + tid);
    f32x4 gd  = *((const f32x4*)(Gu + 4 * GSTRIDE) + tid);

    f32x4 c, cb, hd;
    #pragma unroll
    for (int j = 0; j < 4; j++) {
        float ci  = gi[j] * gz[j];
        float cbi = gib[j] * gz[j];
        float e   = __expf(-gd[j] * d);
        float cdi = cbi + (ci - cbi) * e;      // |cdi| <= 1, tanh is safe
        float t2  = __expf(2.f * cdi);
        c[j]  = ci;
        cb[j] = cbi;
        hd[j] = go[j] * (1.f - 2.f / (t2 + 1.f));
    }

    float* o = out + (size_t)tb * HID;
    __builtin_nontemporal_store(hd, (f32x4*)(o + 0 * TBH) + tid);
    __builtin_nontemporal_store(c,  (f32x4*)(o + 1 * TBH) + tid);
    __builtin_nontemporal_store(cb, (f32x4*)(o + 2 * TBH) + tid);
    __builtin_nontemporal_store(go, (f32x4*)(o + 3 * TBH) + tid);
    __builtin_nontemporal_store(gd, (f32x4*)(o + 4 * TBH) + tid);
}

// ---------------------------------------------------------------------------
extern "C" void kernel_launch(void* const* d_in, const int* in_sizes, int n_in,
                              void* d_out, int out_size, void* d_ws, size_t ws_size,
                              hipStream_t stream) {
    const int*   ev   = (const int*)d_in[0];
    const float* dur  = (const float*)d_in[1];
    const float* emb  = (const float*)d_in[2];
    const float* Wrec = (const float*)d_in[3];
    const float* brec = (const float*)d_in[4];
    float* out = (float*)d_out;

    // workspace layout:
    //   [0, 2MB)    Ebf  : bf16 [1024][1024]  (rows >=1001 left as poison, unread-garbage path)
    //   [2, 12MB)   Wbf  : bf16 [5120][1024]
    //   [12, 32MB)  G    : fp32 [5][1024][1024] activated gate table
    char* ws = (char*)d_ws;
    uint16_t* Ebf = (uint16_t*)ws;
    uint16_t* Wbf = (uint16_t*)(ws + (size_t)2 * 1024 * 1024);
    float*    G   = (float*)(ws + (size_t)12 * 1024 * 1024);

    convert_kernel<<<dim3(TYPES + NGATES), dim3(256), 0, stream>>>(emb, Wrec, Ebf, Wbf);
    gemm_gates<<<dim3(8, 40), dim3(256), 0, stream>>>(Ebf, Wbf, brec, G);
    expand_kernel<<<dim3(TB), dim3(256), 0, stream>>>(ev, dur, G, out);
}